// Round 1
// baseline (4418.521 us; speedup 1.0000x reference)
//
#include <hip/hip_runtime.h>
#include <math.h>

#define BB 512
#define NN 16
#define CC 256
#define KK 8192
#define BNC (BB*NN*CC)

// distance kernel tiling
#define TM 128
#define TN 128
#define BK 32
#define LDSS 36   // 32 + 4 pad floats: keeps 16B alignment, breaks bank aliasing

// ---------------------------------------------------------------------------
// e_sq[k] = sum_c emb[k][c]^2   (one wave per k)
__global__ void esq_kernel(const float* __restrict__ emb, float* __restrict__ e_sq) {
    int gid  = blockIdx.x * blockDim.x + threadIdx.x;
    int wave = gid >> 6;
    int lane = gid & 63;
    const float4 v = *(const float4*)(emb + (size_t)wave * CC + lane * 4);
    float s = v.x*v.x + v.y*v.y + v.z*v.z + v.w*v.w;
    #pragma unroll
    for (int m = 32; m >= 1; m >>= 1) s += __shfl_xor(s, m, 64);
    if (lane == 0) e_sq[wave] = s;
}

// ---------------------------------------------------------------------------
// pool: rest[row][c] = mean over n in [s,e) of f_rest[b][n][c]; r2[row] = ||rest row||^2
// row = b*pn + p. One block (256 threads = C) per row.
__global__ void pool_kernel(const float* __restrict__ f_rest,
                            float* __restrict__ rest,
                            float* __restrict__ r2, int pn) {
    int row = blockIdx.x;
    int b = row / pn, p = row - b * pn;
    int c = threadIdx.x;
    int s = (p * NN) / pn;
    int e = ((p + 1) * NN + pn - 1) / pn;
    float inv = 1.0f / (float)(e - s);
    const float* base = f_rest + (size_t)b * NN * CC + c;
    float acc = 0.f;
    for (int n = s; n < e; ++n) acc += base[(size_t)n * CC];
    float v = acc * inv;
    rest[(size_t)row * CC + c] = v;
    float sq = v * v;
    #pragma unroll
    for (int m = 32; m >= 1; m >>= 1) sq += __shfl_xor(sq, m, 64);
    __shared__ float red[4];
    int wv = threadIdx.x >> 6, ln = threadIdx.x & 63;
    if (ln == 0) red[wv] = sq;
    __syncthreads();
    if (threadIdx.x == 0) r2[row] = (red[0] + red[1]) + (red[2] + red[3]);
}

// ---------------------------------------------------------------------------
__device__ __forceinline__ unsigned long long shfl_xor_u64(unsigned long long v, int m) {
    unsigned lo = (unsigned)v, hi = (unsigned)(v >> 32);
    lo = __shfl_xor(lo, m, 64);
    hi = __shfl_xor(hi, m, 64);
    return ((unsigned long long)hi << 32) | lo;
}

// distance + argmin: for rows [r0, r0+128) x ks [k0, k0+128), d = (r2+e_sq) - 2*dot,
// argmin merged globally via packed (ordered-float-key<<32 | k) atomicMin (tie -> smallest k)
__global__ __launch_bounds__(256) void dist_kernel(
        const float* __restrict__ rest, const float* __restrict__ emb,
        const float* __restrict__ r2, const float* __restrict__ e_sq,
        unsigned long long* __restrict__ packed) {
    __shared__ float sA[TM * LDSS];
    __shared__ float sB[TN * LDSS];
    const int r0 = blockIdx.x * TM;
    const int k0 = blockIdx.y * TN;
    const int tx = threadIdx.x, ty = threadIdx.y;
    const int tid = ty * 16 + tx;

    float acc[8][8];
    #pragma unroll
    for (int i = 0; i < 8; ++i)
        #pragma unroll
        for (int j = 0; j < 8; ++j) acc[i][j] = 0.f;

    for (int c0 = 0; c0 < CC; c0 += BK) {
        #pragma unroll
        for (int t = 0; t < 4; ++t) {
            int idx = tid + t * 256;        // 0..1023
            int row = idx >> 3, c4 = idx & 7;
            float4 va = *(const float4*)(rest + (size_t)(r0 + row) * CC + c0 + c4 * 4);
            *(float4*)(sA + row * LDSS + c4 * 4) = va;
            float4 vb = *(const float4*)(emb + (size_t)(k0 + row) * CC + c0 + c4 * 4);
            *(float4*)(sB + row * LDSS + c4 * 4) = vb;
        }
        __syncthreads();
        #pragma unroll
        for (int kk = 0; kk < BK; kk += 4) {
            float4 a[8], b[8];
            #pragma unroll
            for (int i = 0; i < 8; ++i)
                a[i] = *(const float4*)(sA + (i * 16 + ty) * LDSS + kk);
            #pragma unroll
            for (int j = 0; j < 8; ++j)
                b[j] = *(const float4*)(sB + (j * 16 + tx) * LDSS + kk);
            #pragma unroll
            for (int i = 0; i < 8; ++i) {
                #pragma unroll
                for (int j = 0; j < 8; ++j) {
                    float s = acc[i][j];
                    s = fmaf(a[i].x, b[j].x, s);
                    s = fmaf(a[i].y, b[j].y, s);
                    s = fmaf(a[i].z, b[j].z, s);
                    s = fmaf(a[i].w, b[j].w, s);
                    acc[i][j] = s;
                }
            }
        }
        __syncthreads();
    }

    #pragma unroll
    for (int i = 0; i < 8; ++i) {
        int row = r0 + i * 16 + ty;
        float rr = r2[row];
        unsigned long long best = ~0ull;
        #pragma unroll
        for (int j = 0; j < 8; ++j) {
            int k = k0 + j * 16 + tx;
            float d = (rr + e_sq[k]) - 2.0f * acc[i][j];
            unsigned u = __float_as_uint(d);
            u = (u & 0x80000000u) ? ~u : (u | 0x80000000u);
            unsigned long long p = ((unsigned long long)u << 32) | (unsigned)k;
            if (p < best) best = p;
        }
        #pragma unroll
        for (int m = 1; m < 16; m <<= 1) {
            unsigned long long o = shfl_xor_u64(best, m);
            if (o < best) best = o;
        }
        if (tx == 0) atomicMin(&packed[row], best);
    }
}

// ---------------------------------------------------------------------------
// gather codebook rows, linear-upsample pn->N, f_hat += h, f_rest -= h,
// accumulate sum((f_hat - f)^2) into 256 slots. One block per (b, n).
__global__ void update_kernel(const float* __restrict__ f,
                              const float* __restrict__ emb,
                              const unsigned long long* __restrict__ packed,
                              float* __restrict__ f_rest,
                              float* __restrict__ f_hat,
                              float* __restrict__ slots, int pn) {
    int blk = blockIdx.x;          // b*N + n
    int b = blk >> 4, n = blk & 15;
    int c = threadIdx.x;
    // linear-interp weights (match reference _up_mat, computed in fp64)
    double pos = (n + 0.5) * ((double)pn / 16.0) - 0.5;
    if (pos < 0.0) pos = 0.0;
    int i0 = (int)floor(pos);
    if (i0 > pn - 1) i0 = pn - 1;
    int i1 = i0 + 1;
    if (i1 > pn - 1) i1 = pn - 1;
    double frac = pos - (double)i0;
    float w1 = (float)frac;
    float w0 = (float)(1.0 - frac);
    int k0i = (int)(unsigned)(packed[b * pn + i0] & 0xffffffffull);
    int k1i = (int)(unsigned)(packed[b * pn + i1] & 0xffffffffull);
    float h = w0 * emb[(size_t)k0i * CC + c] + w1 * emb[(size_t)k1i * CC + c];
    size_t off = (size_t)blk * CC + c;
    float fh = f_hat[off] + h;
    f_hat[off] = fh;
    f_rest[off] = f_rest[off] - h;
    float diff = fh - f[off];
    float sq = diff * diff;
    #pragma unroll
    for (int m = 32; m >= 1; m >>= 1) sq += __shfl_xor(sq, m, 64);
    __shared__ float red[4];
    int wv = threadIdx.x >> 6, ln = threadIdx.x & 63;
    if (ln == 0) red[wv] = sq;
    __syncthreads();
    if (threadIdx.x == 0)
        atomicAdd(&slots[blk & 255], (red[0] + red[1]) + (red[2] + red[3]));
}

// ---------------------------------------------------------------------------
__global__ void final_kernel(const float* __restrict__ slots, float* __restrict__ out_scalars) {
    float v = slots[threadIdx.x];
    #pragma unroll
    for (int m = 32; m >= 1; m >>= 1) v += __shfl_xor(v, m, 64);
    __shared__ float red[4];
    int wv = threadIdx.x >> 6, ln = threadIdx.x & 63;
    if (ln == 0) red[wv] = v;
    __syncthreads();
    if (threadIdx.x == 0) {
        float S = (red[0] + red[1]) + (red[2] + red[3]);
        float qlat = S / (float)BNC / (float)NN;
        out_scalars[0] = 0.25f * qlat;   // commit
        out_scalars[1] = qlat;           // qlat
    }
}

// ---------------------------------------------------------------------------
extern "C" void kernel_launch(void* const* d_in, const int* in_sizes, int n_in,
                              void* d_out, int out_size, void* d_ws, size_t ws_size,
                              hipStream_t stream) {
    (void)in_sizes; (void)n_in; (void)out_size; (void)ws_size;
    const float* f   = (const float*)d_in[0];   // [B, N, C]
    const float* emb = (const float*)d_in[1];   // [K, C]
    float* out = (float*)d_out;                 // [B*N*C] f_hat + 2 scalars

    float* ws      = (float*)d_ws;
    float* f_rest  = ws;                    // BNC
    float* rest    = f_rest + BNC;          // BNC (max rows B*N x C)
    float* r2      = rest + BNC;            // B*N
    float* e_sq    = r2 + BB * NN;          // K
    float* slots   = e_sq + KK;             // 256
    unsigned long long* packed = (unsigned long long*)(slots + 256);  // B*N entries

    float* f_hat = out;  // accumulate output in place

    hipMemsetAsync(out, 0, (size_t)BNC * sizeof(float), stream);
    hipMemcpyAsync(f_rest, f, (size_t)BNC * sizeof(float), hipMemcpyDeviceToDevice, stream);
    hipMemsetAsync(slots, 0, 256 * sizeof(float), stream);
    esq_kernel<<<KK / 4, 256, 0, stream>>>(emb, e_sq);

    for (int pn = 1; pn <= NN; ++pn) {
        int R = BB * pn;
        hipMemsetAsync(packed, 0xFF, (size_t)R * sizeof(unsigned long long), stream);
        pool_kernel<<<R, 256, 0, stream>>>(f_rest, rest, r2, pn);
        dim3 grid(R / TM, KK / TN);
        dist_kernel<<<grid, dim3(16, 16), 0, stream>>>(rest, emb, r2, e_sq, packed);
        update_kernel<<<BB * NN, 256, 0, stream>>>(f, emb, packed, f_rest, f_hat, slots, pn);
    }
    final_kernel<<<1, 256, 0, stream>>>(slots, out + BNC);
}

// Round 2
// 1365.559 us; speedup vs baseline: 3.2357x; 3.2357x over previous
//
#include <hip/hip_runtime.h>
#include <math.h>

#define BB 512
#define NN 16
#define CC 256
#define KK 8192
#define BNC (BB*NN*CC)

#define TM 128
#define TN 128

typedef unsigned short u16;
typedef __attribute__((ext_vector_type(8))) short bf16x8;
typedef __attribute__((ext_vector_type(4))) float f32x4;

__device__ __forceinline__ u16 f2bf(float x) {
    unsigned u = __float_as_uint(x);
    unsigned r = (u + 0x7fffu + ((u >> 16) & 1u)) >> 16;
    return (u16)r;
}

__device__ __forceinline__ void gl2lds16(const void* g, void* l) {
    __builtin_amdgcn_global_load_lds(
        (const __attribute__((address_space(1))) void*)g,
        (__attribute__((address_space(3))) void*)l,
        16, 0, 0);
}

// ---------------------------------------------------------------------------
// e_sq[k] = sum_c emb[k][c]^2  (fp32, matches reference)
__global__ void esq_kernel(const float* __restrict__ emb, float* __restrict__ e_sq) {
    int gid  = blockIdx.x * blockDim.x + threadIdx.x;
    int wave = gid >> 6;
    int lane = gid & 63;
    const float4 v = *(const float4*)(emb + (size_t)wave * CC + lane * 4);
    float s = v.x*v.x + v.y*v.y + v.z*v.z + v.w*v.w;
    #pragma unroll
    for (int m = 32; m >= 1; m >>= 1) s += __shfl_xor(s, m, 64);
    if (lane == 0) e_sq[wave] = s;
}

// emb fp32 -> bf16 (RNE), 4 elems/thread
__global__ void cvt_emb_kernel(const float* __restrict__ emb, u16* __restrict__ out) {
    int gid = blockIdx.x * blockDim.x + threadIdx.x;
    float4 v = ((const float4*)emb)[gid];
    ushort4 o;
    o.x = f2bf(v.x); o.y = f2bf(v.y); o.z = f2bf(v.z); o.w = f2bf(v.w);
    ((ushort4*)out)[gid] = o;
}

// ---------------------------------------------------------------------------
// pool: v = mean over n-window of f_rest[b][n][c]; write bf16(v) and fp32 row norm
__global__ void pool_kernel(const float* __restrict__ f_rest,
                            u16* __restrict__ rest_bf,
                            float* __restrict__ r2, int pn) {
    int row = blockIdx.x;
    int b = row / pn, p = row - b * pn;
    int c = threadIdx.x;
    int s = (p * NN) / pn;
    int e = ((p + 1) * NN + pn - 1) / pn;
    float inv = 1.0f / (float)(e - s);
    const float* base = f_rest + (size_t)b * NN * CC + c;
    float acc = 0.f;
    for (int n = s; n < e; ++n) acc += base[(size_t)n * CC];
    float v = acc * inv;
    rest_bf[(size_t)row * CC + c] = f2bf(v);
    float sq = v * v;
    #pragma unroll
    for (int m = 32; m >= 1; m >>= 1) sq += __shfl_xor(sq, m, 64);
    __shared__ float red[4];
    int wv = threadIdx.x >> 6, ln = threadIdx.x & 63;
    if (ln == 0) red[wv] = sq;
    __syncthreads();
    if (threadIdx.x == 0) r2[row] = (red[0] + red[1]) + (red[2] + red[3]);
}

// ---------------------------------------------------------------------------
__device__ __forceinline__ unsigned long long shfl_xor_u64(unsigned long long v, int m) {
    unsigned lo = (unsigned)v, hi = (unsigned)(v >> 32);
    lo = __shfl_xor(lo, m, 64);
    hi = __shfl_xor(hi, m, 64);
    return ((unsigned long long)hi << 32) | lo;
}

// MFMA distance + argmin. 128x128 tile, 4 waves in 2x2, 64x64 per wave (4x4 of
// 16x16x32 bf16 MFMA). d = (r2 + e_sq) - 2*dot (fp32 epilogue, matches ref order).
// Argmin merged via packed (ordered-float<<32 | k) atomicMin (tie -> smallest k).
__global__ __launch_bounds__(256) void dist_mfma_kernel(
        const u16* __restrict__ rest_bf, const u16* __restrict__ emb_bf,
        const float* __restrict__ r2, const float* __restrict__ e_sq,
        unsigned long long* __restrict__ packed) {
    __shared__ u16 sA[TM * 32];   // 8 KB, layout [row][k] contiguous (global_load_lds order)
    __shared__ u16 sB[TN * 32];   // 8 KB
    const int tid = threadIdx.x;
    const int w = tid >> 6, l = tid & 63;
    const int wm = w & 1, wn = w >> 1;
    const int r0  = blockIdx.x * TM;
    const int kb0 = blockIdx.y * TN;

    f32x4 acc[4][4];
    const f32x4 z = {0.f, 0.f, 0.f, 0.f};
    #pragma unroll
    for (int i = 0; i < 4; ++i)
        #pragma unroll
        for (int j = 0; j < 4; ++j) acc[i][j] = z;

    const size_t abase = (size_t)r0 * CC;
    const size_t bbase = (size_t)kb0 * CC;

    for (int k0 = 0; k0 < CC; k0 += 32) {
        #pragma unroll
        for (int i = 0; i < 2; ++i) {
            int chunk = i * 4 + w;                 // 0..7, wave-uniform
            int e = chunk * 64 + l;                // 0..511
            int row = e >> 2, col = (e & 3) * 8;   // 8 bf16 = 16 B per lane
            gl2lds16(rest_bf + abase + (size_t)row * CC + k0 + col,
                     (char*)sA + chunk * 1024);
            gl2lds16(emb_bf + bbase + (size_t)row * CC + k0 + col,
                     (char*)sB + chunk * 1024);
        }
        __syncthreads();   // compiler emits vmcnt(0) drain before barrier

        const int koff = (l >> 4) * 8;
        const int mrow = wm * 64 + (l & 15);
        const int ncol = wn * 64 + (l & 15);
        bf16x8 a[4], b[4];
        #pragma unroll
        for (int t = 0; t < 4; ++t) {
            a[t] = *(const bf16x8*)(sA + (mrow + t * 16) * 32 + koff);
            b[t] = *(const bf16x8*)(sB + (ncol + t * 16) * 32 + koff);
        }
        #pragma unroll
        for (int i = 0; i < 4; ++i)
            #pragma unroll
            for (int j = 0; j < 4; ++j)
                acc[i][j] = __builtin_amdgcn_mfma_f32_16x16x32_bf16(
                                a[i], b[j], acc[i][j], 0, 0, 0);
        __syncthreads();
    }

    // epilogue: C/D layout col = l&15, row = (l>>4)*4 + r
    #pragma unroll
    for (int i = 0; i < 4; ++i) {
        #pragma unroll
        for (int r = 0; r < 4; ++r) {
            int row = r0 + wm * 64 + i * 16 + (l >> 4) * 4 + r;
            float rr = r2[row];
            unsigned long long best = ~0ull;
            #pragma unroll
            for (int j = 0; j < 4; ++j) {
                int k = kb0 + wn * 64 + j * 16 + (l & 15);
                float d = (rr + e_sq[k]) - 2.0f * acc[i][j][r];
                unsigned u = __float_as_uint(d);
                u = (u & 0x80000000u) ? ~u : (u | 0x80000000u);
                unsigned long long p = ((unsigned long long)u << 32) | (unsigned)k;
                if (p < best) best = p;
            }
            #pragma unroll
            for (int m = 1; m < 16; m <<= 1) {
                unsigned long long o = shfl_xor_u64(best, m);
                if (o < best) best = o;
            }
            if ((l & 15) == 0) atomicMin(&packed[row], best);
        }
    }
}

// ---------------------------------------------------------------------------
// gather codebook rows (fp32 emb), linear-upsample pn->N, f_hat += h,
// f_rest -= h, accumulate sum((f_hat - f)^2) into 256 slots.
__global__ void update_kernel(const float* __restrict__ f,
                              const float* __restrict__ emb,
                              const unsigned long long* __restrict__ packed,
                              float* __restrict__ f_rest,
                              float* __restrict__ f_hat,
                              float* __restrict__ slots, int pn) {
    int blk = blockIdx.x;          // b*N + n
    int b = blk >> 4, n = blk & 15;
    int c = threadIdx.x;
    double pos = (n + 0.5) * ((double)pn / 16.0) - 0.5;
    if (pos < 0.0) pos = 0.0;
    int i0 = (int)floor(pos);
    if (i0 > pn - 1) i0 = pn - 1;
    int i1 = i0 + 1;
    if (i1 > pn - 1) i1 = pn - 1;
    double frac = pos - (double)i0;
    float w1 = (float)frac;
    float w0 = (float)(1.0 - frac);
    int k0i = (int)(unsigned)(packed[b * pn + i0] & 0xffffffffull);
    int k1i = (int)(unsigned)(packed[b * pn + i1] & 0xffffffffull);
    float h = w0 * emb[(size_t)k0i * CC + c] + w1 * emb[(size_t)k1i * CC + c];
    size_t off = (size_t)blk * CC + c;
    float fh = f_hat[off] + h;
    f_hat[off] = fh;
    f_rest[off] = f_rest[off] - h;
    float diff = fh - f[off];
    float sq = diff * diff;
    #pragma unroll
    for (int m = 32; m >= 1; m >>= 1) sq += __shfl_xor(sq, m, 64);
    __shared__ float red[4];
    int wv = threadIdx.x >> 6, ln = threadIdx.x & 63;
    if (ln == 0) red[wv] = sq;
    __syncthreads();
    if (threadIdx.x == 0)
        atomicAdd(&slots[blk & 255], (red[0] + red[1]) + (red[2] + red[3]));
}

// ---------------------------------------------------------------------------
__global__ void final_kernel(const float* __restrict__ slots, float* __restrict__ out_scalars) {
    float v = slots[threadIdx.x];
    #pragma unroll
    for (int m = 32; m >= 1; m >>= 1) v += __shfl_xor(v, m, 64);
    __shared__ float red[4];
    int wv = threadIdx.x >> 6, ln = threadIdx.x & 63;
    if (ln == 0) red[wv] = v;
    __syncthreads();
    if (threadIdx.x == 0) {
        float S = (red[0] + red[1]) + (red[2] + red[3]);
        float qlat = S / (float)BNC / (float)NN;
        out_scalars[0] = 0.25f * qlat;   // commit
        out_scalars[1] = qlat;           // qlat
    }
}

// ---------------------------------------------------------------------------
extern "C" void kernel_launch(void* const* d_in, const int* in_sizes, int n_in,
                              void* d_out, int out_size, void* d_ws, size_t ws_size,
                              hipStream_t stream) {
    (void)in_sizes; (void)n_in; (void)out_size; (void)ws_size;
    const float* f   = (const float*)d_in[0];   // [B, N, C]
    const float* emb = (const float*)d_in[1];   // [K, C]
    float* out = (float*)d_out;                 // f_hat [B*N*C] + 2 scalars

    float* ws      = (float*)d_ws;
    float* f_rest  = ws;                                   // BNC floats
    float* r2      = f_rest + BNC;                         // B*N
    float* e_sq    = r2 + BB * NN;                         // K
    float* slots   = e_sq + KK;                            // 256
    unsigned long long* packed = (unsigned long long*)(slots + 256);   // B*N
    u16* rest_bf = (u16*)(packed + BB * NN);               // B*N*C bf16
    u16* emb_bf  = rest_bf + (size_t)BB * NN * CC;         // K*C bf16

    float* f_hat = out;  // accumulate output in place

    hipMemsetAsync(out, 0, (size_t)BNC * sizeof(float), stream);
    hipMemcpyAsync(f_rest, f, (size_t)BNC * sizeof(float), hipMemcpyDeviceToDevice, stream);
    hipMemsetAsync(slots, 0, 256 * sizeof(float), stream);
    esq_kernel<<<KK / 4, 256, 0, stream>>>(emb, e_sq);
    cvt_emb_kernel<<<KK * CC / 4 / 256, 256, 0, stream>>>(emb, emb_bf);

    for (int pn = 1; pn <= NN; ++pn) {
        int R = BB * pn;
        hipMemsetAsync(packed, 0xFF, (size_t)R * sizeof(unsigned long long), stream);
        pool_kernel<<<R, 256, 0, stream>>>(f_rest, rest_bf, r2, pn);
        dim3 grid(R / TM, KK / TN);
        dist_mfma_kernel<<<grid, 256, 0, stream>>>(rest_bf, emb_bf, r2, e_sq, packed);
        update_kernel<<<BB * NN, 256, 0, stream>>>(f, emb, packed, f_rest, f_hat, slots, pn);
    }
    final_kernel<<<1, 256, 0, stream>>>(slots, out + BNC);
}

// Round 3
// 1340.739 us; speedup vs baseline: 3.2956x; 1.0185x over previous
//
#include <hip/hip_runtime.h>
#include <math.h>

#define BB 512
#define NN 16
#define CC 256
#define KK 8192
#define BNC (BB*NN*CC)

#define TM 128
#define TN 128

typedef unsigned short u16;
typedef __attribute__((ext_vector_type(8))) short bf16x8;
typedef __attribute__((ext_vector_type(4))) float f32x4;

__device__ __forceinline__ u16 f2bf(float x) {
    unsigned u = __float_as_uint(x);
    unsigned r = (u + 0x7fffu + ((u >> 16) & 1u)) >> 16;
    return (u16)r;
}

__device__ __forceinline__ void gl2lds16(const void* g, void* l) {
    __builtin_amdgcn_global_load_lds(
        (const __attribute__((address_space(1))) void*)g,
        (__attribute__((address_space(3))) void*)l,
        16, 0, 0);
}

// ---------------------------------------------------------------------------
// e_sq[k] = sum_c emb[k][c]^2  (fp32, matches reference)
__global__ void esq_kernel(const float* __restrict__ emb, float* __restrict__ e_sq) {
    int gid  = blockIdx.x * blockDim.x + threadIdx.x;
    int wave = gid >> 6;
    int lane = gid & 63;
    const float4 v = *(const float4*)(emb + (size_t)wave * CC + lane * 4);
    float s = v.x*v.x + v.y*v.y + v.z*v.z + v.w*v.w;
    #pragma unroll
    for (int m = 32; m >= 1; m >>= 1) s += __shfl_xor(s, m, 64);
    if (lane == 0) e_sq[wave] = s;
}

// emb fp32 -> bf16 (RNE)
__global__ void cvt_emb_kernel(const float* __restrict__ emb, u16* __restrict__ out) {
    int gid = blockIdx.x * blockDim.x + threadIdx.x;
    float4 v = ((const float4*)emb)[gid];
    ushort4 o;
    o.x = f2bf(v.x); o.y = f2bf(v.y); o.z = f2bf(v.z); o.w = f2bf(v.w);
    ((ushort4*)out)[gid] = o;
}

// ---------------------------------------------------------------------------
// initial pool for pn=1: rest row b = mean over all 16 n of f[b][n][c]
__global__ void init_pool_kernel(const float* __restrict__ f,
                                 u16* __restrict__ rest_bf,
                                 float* __restrict__ r2) {
    int b = blockIdx.x;
    int c = threadIdx.x;
    const float* base = f + (size_t)b * NN * CC + c;
    float acc = 0.f;
    #pragma unroll
    for (int n = 0; n < NN; ++n) acc += base[(size_t)n * CC];
    float v = acc * (1.0f / 16.0f);
    rest_bf[(size_t)b * CC + c] = f2bf(v);
    float sq = v * v;
    #pragma unroll
    for (int m = 32; m >= 1; m >>= 1) sq += __shfl_xor(sq, m, 64);
    __shared__ float red[4];
    int wv = threadIdx.x >> 6, ln = threadIdx.x & 63;
    if (ln == 0) red[wv] = sq;
    __syncthreads();
    if (threadIdx.x == 0) r2[b] = (red[0] + red[1]) + (red[2] + red[3]);
}

// ---------------------------------------------------------------------------
__device__ __forceinline__ unsigned long long shfl_xor_u64(unsigned long long v, int m) {
    unsigned lo = (unsigned)v, hi = (unsigned)(v >> 32);
    lo = __shfl_xor(lo, m, 64);
    hi = __shfl_xor(hi, m, 64);
    return ((unsigned long long)hi << 32) | lo;
}

// MFMA distance + argmin. 128x128 tile, BK=64 (4 K-iters), XOR-swizzled LDS
// columns (swizzle applied in the global fetch mapping so global_load_lds'
// lane-contiguous constraint is satisfied; read side XORs the same mask).
__global__ __launch_bounds__(256) void dist_mfma_kernel(
        const u16* __restrict__ rest_bf, const u16* __restrict__ emb_bf,
        const float* __restrict__ r2, const float* __restrict__ e_sq,
        unsigned long long* __restrict__ packed) {
    __shared__ u16 sA[TM * 64];   // 16 KB, [row][64 k] with column-XOR swizzle
    __shared__ u16 sB[TN * 64];   // 16 KB
    const int tid = threadIdx.x;
    const int w = tid >> 6, l = tid & 63;
    const int wm = w & 1, wn = w >> 1;
    const int r0  = blockIdx.x * TM;
    const int kb0 = blockIdx.y * TN;

    f32x4 acc[4][4];
    const f32x4 z = {0.f, 0.f, 0.f, 0.f};
    #pragma unroll
    for (int i = 0; i < 4; ++i)
        #pragma unroll
        for (int j = 0; j < 4; ++j) acc[i][j] = z;

    const size_t abase = (size_t)r0 * CC;
    const size_t bbase = (size_t)kb0 * CC;

    // per-lane fetch mapping for staging: chunk = 8 rows x 128 B
    const int srow = l >> 3;                    // 0..7 within chunk
    const int skcol = ((l & 7) ^ srow) * 8;     // XOR-swizzled k column (u16 units)
    const int mrow = wm * 64 + (l & 15);
    const int ncol = wn * 64 + (l & 15);
    const int xm = l & 7;                       // read-side XOR mask (== row&7)

    for (int k0 = 0; k0 < CC; k0 += 64) {
        #pragma unroll
        for (int i = 0; i < 4; ++i) {
            int chunk = w * 4 + i;              // 0..15, wave-uniform
            int row = chunk * 8 + srow;
            gl2lds16(rest_bf + abase + (size_t)row * CC + k0 + skcol,
                     (char*)sA + chunk * 1024);
            gl2lds16(emb_bf + bbase + (size_t)row * CC + k0 + skcol,
                     (char*)sB + chunk * 1024);
        }
        __syncthreads();

        #pragma unroll
        for (int ksub = 0; ksub < 2; ++ksub) {
            const int kg = (ksub * 4 + (l >> 4)) ^ xm;   // physical column group
            bf16x8 a[4], b[4];
            #pragma unroll
            for (int t = 0; t < 4; ++t) {
                a[t] = *(const bf16x8*)(sA + (mrow + t * 16) * 64 + kg * 8);
                b[t] = *(const bf16x8*)(sB + (ncol + t * 16) * 64 + kg * 8);
            }
            #pragma unroll
            for (int i = 0; i < 4; ++i)
                #pragma unroll
                for (int j = 0; j < 4; ++j)
                    acc[i][j] = __builtin_amdgcn_mfma_f32_16x16x32_bf16(
                                    a[i], b[j], acc[i][j], 0, 0, 0);
        }
        __syncthreads();
    }

    // epilogue: C/D layout col = l&15, row = (l>>4)*4 + r
    #pragma unroll
    for (int i = 0; i < 4; ++i) {
        #pragma unroll
        for (int r = 0; r < 4; ++r) {
            int row = r0 + wm * 64 + i * 16 + (l >> 4) * 4 + r;
            float rr = r2[row];
            unsigned long long best = ~0ull;
            #pragma unroll
            for (int j = 0; j < 4; ++j) {
                int k = kb0 + wn * 64 + j * 16 + (l & 15);
                float d = (rr + e_sq[k]) - 2.0f * acc[i][j][r];
                unsigned u = __float_as_uint(d);
                u = (u & 0x80000000u) ? ~u : (u | 0x80000000u);
                unsigned long long p = ((unsigned long long)u << 32) | (unsigned)k;
                if (p < best) best = p;
            }
            #pragma unroll
            for (int m = 1; m < 16; m <<= 1) {
                unsigned long long o = shfl_xor_u64(best, m);
                if (o < best) best = o;
            }
            if ((l & 15) == 0) atomicMin(&packed[row], best);
        }
    }
}

// ---------------------------------------------------------------------------
// Fused: gather + upsample + f_hat/f_rest update + qlat partial + pool for pn+1.
// One block per batch b; each thread owns channel c across all 16 n.
__global__ void update_pool_kernel(const float* __restrict__ f,
                                   const float* __restrict__ emb,
                                   const unsigned long long* __restrict__ packed,
                                   float* __restrict__ f_rest,
                                   float* __restrict__ f_hat,
                                   float* __restrict__ slots,
                                   u16* __restrict__ rest_bf,
                                   float* __restrict__ r2, int pn) {
    int b = blockIdx.x;
    int c = threadIdx.x;
    __shared__ int sk[NN];
    __shared__ float red[4];
    __shared__ float red2[NN + 1][4];
    if (threadIdx.x < pn)
        sk[threadIdx.x] = (int)(unsigned)(packed[b * pn + threadIdx.x] & 0xffffffffull);
    __syncthreads();

    float fr[NN];
    float acc_sq = 0.f;
    #pragma unroll
    for (int n = 0; n < NN; ++n) {
        double pos = (n + 0.5) * ((double)pn / 16.0) - 0.5;
        if (pos < 0.0) pos = 0.0;
        int i0 = (int)floor(pos);
        if (i0 > pn - 1) i0 = pn - 1;
        int i1 = i0 + 1;
        if (i1 > pn - 1) i1 = pn - 1;
        double frac = pos - (double)i0;
        float w1 = (float)frac;
        float w0 = (float)(1.0 - frac);
        float h = w0 * emb[(size_t)sk[i0] * CC + c] + w1 * emb[(size_t)sk[i1] * CC + c];
        size_t off = ((size_t)b * NN + n) * CC + c;
        float fh = f_hat[off] + h;
        f_hat[off] = fh;
        float fre = f_rest[off] - h;
        f_rest[off] = fre;
        fr[n] = fre;
        float diff = fh - f[off];
        acc_sq += diff * diff;
    }

    int wv = threadIdx.x >> 6, ln = threadIdx.x & 63;
    #pragma unroll
    for (int m = 32; m >= 1; m >>= 1) acc_sq += __shfl_xor(acc_sq, m, 64);
    if (ln == 0) red[wv] = acc_sq;

    int pn2 = pn + 1;
    if (pn < NN) {
        for (int p = 0; p < pn2; ++p) {
            int s = (p * NN) / pn2;
            int e = ((p + 1) * NN + pn2 - 1) / pn2;
            float v = 0.f;
            for (int n = s; n < e; ++n) v += fr[n];
            v *= 1.0f / (float)(e - s);
            rest_bf[((size_t)(b * pn2 + p)) * CC + c] = f2bf(v);
            float sq = v * v;
            #pragma unroll
            for (int m = 32; m >= 1; m >>= 1) sq += __shfl_xor(sq, m, 64);
            if (ln == 0) red2[p][wv] = sq;
        }
    }
    __syncthreads();
    if (threadIdx.x == 0)
        atomicAdd(&slots[b & 255], (red[0] + red[1]) + (red[2] + red[3]));
    if (pn < NN && threadIdx.x < pn2) {
        int p = threadIdx.x;
        r2[b * pn2 + p] = (red2[p][0] + red2[p][1]) + (red2[p][2] + red2[p][3]);
    }
}

// ---------------------------------------------------------------------------
__global__ void final_kernel(const float* __restrict__ slots, float* __restrict__ out_scalars) {
    float v = slots[threadIdx.x];
    #pragma unroll
    for (int m = 32; m >= 1; m >>= 1) v += __shfl_xor(v, m, 64);
    __shared__ float red[4];
    int wv = threadIdx.x >> 6, ln = threadIdx.x & 63;
    if (ln == 0) red[wv] = v;
    __syncthreads();
    if (threadIdx.x == 0) {
        float S = (red[0] + red[1]) + (red[2] + red[3]);
        float qlat = S / (float)BNC / (float)NN;
        out_scalars[0] = 0.25f * qlat;   // commit
        out_scalars[1] = qlat;           // qlat
    }
}

// ---------------------------------------------------------------------------
extern "C" void kernel_launch(void* const* d_in, const int* in_sizes, int n_in,
                              void* d_out, int out_size, void* d_ws, size_t ws_size,
                              hipStream_t stream) {
    (void)in_sizes; (void)n_in; (void)out_size; (void)ws_size;
    const float* f   = (const float*)d_in[0];   // [B, N, C]
    const float* emb = (const float*)d_in[1];   // [K, C]
    float* out = (float*)d_out;                 // f_hat [B*N*C] + 2 scalars

    float* ws      = (float*)d_ws;
    float* f_rest  = ws;                                   // BNC floats
    float* r2      = f_rest + BNC;                         // 8192
    float* e_sq    = r2 + BB * NN;                         // K
    float* slots   = e_sq + KK;                            // 256
    unsigned long long* packed_all = (unsigned long long*)(slots + 256);  // 512*136
    u16* rest_bf = (u16*)(packed_all + (size_t)BB * 136);  // 8192*256 bf16
    u16* emb_bf  = rest_bf + (size_t)BB * NN * CC;         // K*C bf16

    float* f_hat = out;  // accumulate output in place

    hipMemsetAsync(out, 0, (size_t)BNC * sizeof(float), stream);
    hipMemcpyAsync(f_rest, f, (size_t)BNC * sizeof(float), hipMemcpyDeviceToDevice, stream);
    hipMemsetAsync(slots, 0, 256 * sizeof(float), stream);
    hipMemsetAsync(packed_all, 0xFF, (size_t)BB * 136 * sizeof(unsigned long long), stream);
    esq_kernel<<<KK / 4, 256, 0, stream>>>(emb, e_sq);
    cvt_emb_kernel<<<KK * CC / 4 / 256, 256, 0, stream>>>(emb, emb_bf);
    init_pool_kernel<<<BB, 256, 0, stream>>>(f, rest_bf, r2);

    for (int pn = 1; pn <= NN; ++pn) {
        int R = BB * pn;
        unsigned long long* packed = packed_all + (size_t)BB * (pn * (pn - 1) / 2);
        dim3 grid(R / TM, KK / TN);
        dist_mfma_kernel<<<grid, 256, 0, stream>>>(rest_bf, emb_bf, r2, e_sq, packed);
        update_pool_kernel<<<BB, 256, 0, stream>>>(f, emb, packed, f_rest, f_hat,
                                                   slots, rest_bf, r2, pn);
    }
    final_kernel<<<1, 256, 0, stream>>>(slots, out + BNC);
}

// Round 4
// 820.534 us; speedup vs baseline: 5.3849x; 1.6340x over previous
//
#include <hip/hip_runtime.h>
#include <math.h>

#define BB 512
#define NN 16
#define CC 256
#define KK 8192
#define BNC (BB*NN*CC)

typedef unsigned short u16;
typedef __attribute__((ext_vector_type(8))) short bf16x8;
typedef __attribute__((ext_vector_type(4))) float f32x4;

__device__ __forceinline__ u16 f2bf(float x) {
    unsigned u = __float_as_uint(x);
    unsigned r = (u + 0x7fffu + ((u >> 16) & 1u)) >> 16;
    return (u16)r;
}

__device__ __forceinline__ void gl2lds16(const void* g, void* l) {
    __builtin_amdgcn_global_load_lds(
        (const __attribute__((address_space(1))) void*)g,
        (__attribute__((address_space(3))) void*)l,
        16, 0, 0);
}

// ---------------------------------------------------------------------------
__global__ void esq_kernel(const float* __restrict__ emb, float* __restrict__ e_sq) {
    int gid  = blockIdx.x * blockDim.x + threadIdx.x;
    int wave = gid >> 6;
    int lane = gid & 63;
    const float4 v = *(const float4*)(emb + (size_t)wave * CC + lane * 4);
    float s = v.x*v.x + v.y*v.y + v.z*v.z + v.w*v.w;
    #pragma unroll
    for (int m = 32; m >= 1; m >>= 1) s += __shfl_xor(s, m, 64);
    if (lane == 0) e_sq[wave] = s;
}

__global__ void cvt_emb_kernel(const float* __restrict__ emb, u16* __restrict__ out) {
    int gid = blockIdx.x * blockDim.x + threadIdx.x;
    float4 v = ((const float4*)emb)[gid];
    ushort4 o;
    o.x = f2bf(v.x); o.y = f2bf(v.y); o.z = f2bf(v.z); o.w = f2bf(v.w);
    ((ushort4*)out)[gid] = o;
}

// initial pool for pn=1
__global__ void init_pool_kernel(const float* __restrict__ f,
                                 u16* __restrict__ rest_bf) {
    int b = blockIdx.x;
    int c = threadIdx.x;
    const float* base = f + (size_t)b * NN * CC + c;
    float acc = 0.f;
    #pragma unroll
    for (int n = 0; n < NN; ++n) acc += base[(size_t)n * CC];
    rest_bf[(size_t)b * CC + c] = f2bf(acc * (1.0f / 16.0f));
}

// ---------------------------------------------------------------------------
__device__ __forceinline__ unsigned long long shfl_xor_u64(unsigned long long v, int m) {
    unsigned lo = (unsigned)v, hi = (unsigned)(v >> 32);
    lo = __shfl_xor(lo, m, 64);
    hi = __shfl_xor(hi, m, 64);
    return ((unsigned long long)hi << 32) | lo;
}

// Barrier-free MFMA distance+argmin.
// Block: 64 A-rows resident in LDS (swizzled), 4 waves each own a 64-code strip
// per 256-code group; B staged into wave-private double-buffered LDS via
// global_load_lds (per-wave vmcnt sync only, NO __syncthreads in main loop).
// Per-row argmin kept in registers across the whole code range; one
// shfl-merge + atomicMin per row at the end. Argmin key = e_sq[k] - 2*dot
// (same ordering as ref's r2+e_sq-2*dot; r2 is row-constant).
__global__ __launch_bounds__(256, 2) void dist_mfma_kernel(
        const u16* __restrict__ A, const u16* __restrict__ Bm,
        const float* __restrict__ e_sq,
        unsigned long long* __restrict__ packed, int cpb) {
    __shared__ __align__(16) u16 sA[16384];   // 32 KB: 64 rows x 256 K, swizzled
    __shared__ __align__(16) u16 sB[16384];   // 32 KB: 4 waves x 2 bufs x (64x32)
    const int tid = threadIdx.x;
    const int w = tid >> 6, l = tid & 63;
    const int r0 = blockIdx.x * 64;
    const int c0 = blockIdx.y * cpb;
    const int ncb = cpb >> 8;
    const int arow = l & 15;     // row/col within 16-tile
    const int aq   = l >> 4;     // quad (k-granule selector)

    // ---- stage A once: slot s = row*32 + (g ^ (row&31)), 16B granules ----
    {
        const int phys = tid & 31;
        #pragma unroll
        for (int i = 0; i < 8; ++i) {
            int s = tid + 256 * i;
            int row = s >> 5;
            int g = phys ^ (row & 31);
            gl2lds16(A + (((size_t)(r0 + row)) << 8) + g * 8,
                     (char*)sA + (size_t)(w * 64 + 256 * i) * 16);
        }
    }
    // ---- B staging: lane constants. slot sigma(c,g) = 4c + (g^(c&3)^((c>>2)&3))
    const int gsel = (l & 3) ^ ((l >> 2) & 3) ^ ((l >> 4) & 3);
    const int crow = l >> 2;

    #define STAGE_B(cb_, kc_, buf_)                                            \
        {                                                                      \
            const u16* src = Bm + (((size_t)(c0 + (cb_) * 256 + w * 64)) << 8) \
                             + (kc_) * 32 + gsel * 8;                          \
            char* dst = (char*)sB + ((w * 2 + (buf_)) << 12);                  \
            _Pragma("unroll")                                                  \
            for (int ld = 0; ld < 4; ++ld)                                     \
                gl2lds16(src + ((size_t)(crow + 16 * ld) << 8), dst + (ld << 10)); \
        }

    STAGE_B(0, 0, 0);
    __syncthreads();   // A + first chunk visible; only barrier in the kernel

    float bestd[16];
    int   bestk[16];
    #pragma unroll
    for (int t = 0; t < 16; ++t) { bestd[t] = 1e30f; bestk[t] = 0; }

    for (int cb = 0; cb < ncb; ++cb) {
        f32x4 acc[4][4];
        const f32x4 z = {0.f, 0.f, 0.f, 0.f};
        #pragma unroll
        for (int i = 0; i < 4; ++i)
            #pragma unroll
            for (int j = 0; j < 4; ++j) acc[i][j] = z;

        #pragma unroll
        for (int kc = 0; kc < 8; ++kc) {
            const int buf = kc & 1;
            // wait for this chunk's staging (the only outstanding loads)
            __builtin_amdgcn_s_waitcnt(0x0F70);   // vmcnt(0), lgkm/exp no-wait
            bf16x8 a[4], b[4];
            const u16* wb = sB + ((w * 2 + buf) << 11);
            #pragma unroll
            for (int t = 0; t < 4; ++t) {
                int row = t * 16 + arow;
                int g = kc * 4 + aq;
                int phys = g ^ (row & 31);
                a[t] = *(const bf16x8*)(sA + row * 256 + phys * 8);
                int cc_ = t * 16 + arow;
                int sig = cc_ * 4 + (aq ^ (cc_ & 3) ^ ((cc_ >> 2) & 3));
                b[t] = *(const bf16x8*)(wb + sig * 8);
            }
            // prefetch next chunk into other buffer (overlaps MFMA phase)
            int cbn = (kc == 7) ? ((cb + 1 < ncb) ? cb + 1 : cb) : cb;
            int kcn = (kc + 1) & 7;
            STAGE_B(cbn, kcn, buf ^ 1);
            #pragma unroll
            for (int i = 0; i < 4; ++i)
                #pragma unroll
                for (int j = 0; j < 4; ++j)
                    acc[i][j] = __builtin_amdgcn_mfma_f32_16x16x32_bf16(
                                    a[i], b[j], acc[i][j], 0, 0, 0);
        }

        // fold this 256-code group into running per-lane argmin
        float esq[4];
        #pragma unroll
        for (int j = 0; j < 4; ++j)
            esq[j] = e_sq[c0 + cb * 256 + w * 64 + j * 16 + arow];
        #pragma unroll
        for (int i = 0; i < 4; ++i)
            #pragma unroll
            for (int r = 0; r < 4; ++r) {
                const int slot = i * 4 + r;
                #pragma unroll
                for (int j = 0; j < 4; ++j) {
                    float d = fmaf(-2.0f, acc[i][j][r], esq[j]);
                    int k = c0 + cb * 256 + w * 64 + j * 16 + arow;
                    if (d < bestd[slot]) { bestd[slot] = d; bestk[slot] = k; }
                }
            }
    }

    // cross-lane merge (lanes sharing l>>4 hold same rows) + global merge
    #pragma unroll
    for (int t = 0; t < 16; ++t) {
        unsigned u = __float_as_uint(bestd[t]);
        u = (u & 0x80000000u) ? ~u : (u | 0x80000000u);
        unsigned long long p = ((unsigned long long)u << 32) | (unsigned)bestk[t];
        #pragma unroll
        for (int m = 1; m < 16; m <<= 1) {
            unsigned long long o = shfl_xor_u64(p, m);
            if (o < p) p = o;
        }
        if (arow == 0)
            atomicMin(&packed[r0 + (t >> 2) * 16 + aq * 4 + (t & 3)], p);
    }
    #undef STAGE_B
}

// ---------------------------------------------------------------------------
// Fused: gather + upsample + f_hat/f_rest update + qlat partial + pool for pn+1.
__global__ void update_pool_kernel(const float* __restrict__ f,
                                   const float* __restrict__ emb,
                                   const unsigned long long* __restrict__ packed,
                                   float* __restrict__ f_rest,
                                   float* __restrict__ f_hat,
                                   float* __restrict__ slots,
                                   u16* __restrict__ rest_bf, int pn) {
    int b = blockIdx.x;
    int c = threadIdx.x;
    __shared__ int sk[NN];
    __shared__ float red[4];
    if (threadIdx.x < pn)
        sk[threadIdx.x] = (int)(unsigned)(packed[b * pn + threadIdx.x] & 0xffffffffull);
    __syncthreads();

    float fr[NN];
    float acc_sq = 0.f;
    #pragma unroll
    for (int n = 0; n < NN; ++n) {
        double pos = (n + 0.5) * ((double)pn / 16.0) - 0.5;
        if (pos < 0.0) pos = 0.0;
        int i0 = (int)floor(pos);
        if (i0 > pn - 1) i0 = pn - 1;
        int i1 = i0 + 1;
        if (i1 > pn - 1) i1 = pn - 1;
        double frac = pos - (double)i0;
        float w1 = (float)frac;
        float w0 = (float)(1.0 - frac);
        float h = w0 * emb[(size_t)sk[i0] * CC + c] + w1 * emb[(size_t)sk[i1] * CC + c];
        size_t off = ((size_t)b * NN + n) * CC + c;
        float fh = f_hat[off] + h;
        f_hat[off] = fh;
        float fre = f_rest[off] - h;
        f_rest[off] = fre;
        fr[n] = fre;
        float diff = fh - f[off];
        acc_sq += diff * diff;
    }

    int wv = threadIdx.x >> 6, ln = threadIdx.x & 63;
    #pragma unroll
    for (int m = 32; m >= 1; m >>= 1) acc_sq += __shfl_xor(acc_sq, m, 64);
    if (ln == 0) red[wv] = acc_sq;

    int pn2 = pn + 1;
    if (pn < NN) {
        for (int p = 0; p < pn2; ++p) {
            int s = (p * NN) / pn2;
            int e = ((p + 1) * NN + pn2 - 1) / pn2;
            float v = 0.f;
            for (int n = s; n < e; ++n) v += fr[n];
            v *= 1.0f / (float)(e - s);
            rest_bf[((size_t)(b * pn2 + p)) * CC + c] = f2bf(v);
        }
    }
    __syncthreads();
    if (threadIdx.x == 0)
        atomicAdd(&slots[b & 255], (red[0] + red[1]) + (red[2] + red[3]));
}

// ---------------------------------------------------------------------------
__global__ void final_kernel(const float* __restrict__ slots, float* __restrict__ out_scalars) {
    float v = slots[threadIdx.x];
    #pragma unroll
    for (int m = 32; m >= 1; m >>= 1) v += __shfl_xor(v, m, 64);
    __shared__ float red[4];
    int wv = threadIdx.x >> 6, ln = threadIdx.x & 63;
    if (ln == 0) red[wv] = v;
    __syncthreads();
    if (threadIdx.x == 0) {
        float S = (red[0] + red[1]) + (red[2] + red[3]);
        float qlat = S / (float)BNC / (float)NN;
        out_scalars[0] = 0.25f * qlat;   // commit
        out_scalars[1] = qlat;           // qlat
    }
}

// ---------------------------------------------------------------------------
extern "C" void kernel_launch(void* const* d_in, const int* in_sizes, int n_in,
                              void* d_out, int out_size, void* d_ws, size_t ws_size,
                              hipStream_t stream) {
    (void)in_sizes; (void)n_in; (void)out_size; (void)ws_size;
    const float* f   = (const float*)d_in[0];   // [B, N, C]
    const float* emb = (const float*)d_in[1];   // [K, C]
    float* out = (float*)d_out;                 // f_hat [B*N*C] + 2 scalars

    float* ws      = (float*)d_ws;
    float* f_rest  = ws;                                   // BNC floats
    float* r2_pad  = f_rest + BNC;                         // 8192 (unused, layout keep)
    float* e_sq    = r2_pad + BB * NN;                     // K
    float* slots   = e_sq + KK;                            // 256
    unsigned long long* packed_all = (unsigned long long*)(slots + 256);  // 512*136
    u16* rest_bf = (u16*)(packed_all + (size_t)BB * 136);  // 8192*256 bf16
    u16* emb_bf  = rest_bf + (size_t)BB * NN * CC;         // K*C bf16

    float* f_hat = out;  // accumulate output in place

    hipMemsetAsync(out, 0, (size_t)BNC * sizeof(float), stream);
    hipMemcpyAsync(f_rest, f, (size_t)BNC * sizeof(float), hipMemcpyDeviceToDevice, stream);
    hipMemsetAsync(slots, 0, 256 * sizeof(float), stream);
    hipMemsetAsync(packed_all, 0xFF, (size_t)BB * 136 * sizeof(unsigned long long), stream);
    esq_kernel<<<KK / 4, 256, 0, stream>>>(emb, e_sq);
    cvt_emb_kernel<<<KK * CC / 4 / 256, 256, 0, stream>>>(emb, emb_bf);
    init_pool_kernel<<<BB, 256, 0, stream>>>(f, rest_bf);

    // codebook splits per pn: keep grid >= ~256 blocks, cpb >= 256
    static const int splits_tab[17] = {0,32,32,16,16,8,8,8,8,4,4,4,4,4,4,4,4};

    for (int pn = 1; pn <= NN; ++pn) {
        unsigned long long* packed = packed_all + (size_t)BB * (pn * (pn - 1) / 2);
        int splits = splits_tab[pn];
        int cpb = KK / splits;
        dim3 grid(BB * pn / 64, splits);
        dist_mfma_kernel<<<grid, 256, 0, stream>>>(rest_bf, emb_bf, e_sq, packed, cpb);
        update_pool_kernel<<<BB, 256, 0, stream>>>(f, emb, packed, f_rest, f_hat,
                                                   slots, rest_bf, pn);
    }
    final_kernel<<<1, 256, 0, stream>>>(slots, out + BNC);
}